// Round 5
// baseline (318.608 us; speedup 1.0000x reference)
//
#include <hip/hip_runtime.h>
#include <math.h>
#include <float.h>

#define B_    4
#define N_    2048
#define M_    8192
#define CIN_  512
#define COUT_ 256

// ---------------------------------------------------------------------------
// System-scope relaxed atomics for the d_ws producer->consumer handoff.
// These emit sc0/sc1 (bypass L1 + per-XCD L2, hit the coherence point), making
// inter-kernel visibility independent of graph-replay cache-op behavior.
// ---------------------------------------------------------------------------
__device__ __forceinline__ void ws_store_f32(float* p, float v) {
    __hip_atomic_store((unsigned int*)p, __float_as_uint(v),
                       __ATOMIC_RELAXED, __HIP_MEMORY_SCOPE_SYSTEM);
}
__device__ __forceinline__ void ws_store_u32(int* p, int v) {
    __hip_atomic_store((unsigned int*)p, (unsigned int)v,
                       __ATOMIC_RELAXED, __HIP_MEMORY_SCOPE_SYSTEM);
}
__device__ __forceinline__ float ws_load_f32(const float* p) {
    return __uint_as_float(__hip_atomic_load((const unsigned int*)p,
                       __ATOMIC_RELAXED, __HIP_MEMORY_SCOPE_SYSTEM));
}
__device__ __forceinline__ int ws_load_u32(const int* p) {
    return (int)__hip_atomic_load((const unsigned int*)p,
                       __ATOMIC_RELAXED, __HIP_MEMORY_SCOPE_SYSTEM);
}

// ---------------------------------------------------------------------------
// Kernel A: f1t[b][n][c] = relu( bn( sum_ci w_up[c,ci]*x1[b,ci,n] ) )
// 64x64 output tile per block, 4x4 micro-tile per thread, K-chunks of 32.
// Epilogue transposes through LDS; f1t stores are system-scope (ws handoff).
// ---------------------------------------------------------------------------
__global__ __launch_bounds__(256) void up_conv_kernel(
    const float* __restrict__ x1, const float* __restrict__ w,
    const float* __restrict__ gam, const float* __restrict__ bet,
    const float* __restrict__ mu, const float* __restrict__ var,
    float* __restrict__ f1t)
{
    __shared__ float sm[4224];
    float* Ws = sm;          // [32][68]  Ws[k*68 + o]
    float* Xs = sm + 2176;   // [32][64]  Xs[k*64 + n]
    const int b = blockIdx.z;
    const int o0 = blockIdx.y * 64;
    const int n0 = blockIdx.x * 64;
    const int tid = threadIdx.x;
    const int tx = tid & 15, ty = tid >> 4;

    float acc[4][4] = {{0.f}};

    for (int kc = 0; kc < CIN_; kc += 32) {
        #pragma unroll
        for (int r = 0; r < 2; ++r) {
            int e = tid + r * 256;          // 512 float4 of W tile (64o x 32k)
            int o = e >> 3, k4 = e & 7;
            float4 v = *(const float4*)(w + (size_t)(o0 + o) * CIN_ + kc + k4 * 4);
            Ws[(k4*4+0)*68 + o] = v.x;
            Ws[(k4*4+1)*68 + o] = v.y;
            Ws[(k4*4+2)*68 + o] = v.z;
            Ws[(k4*4+3)*68 + o] = v.w;
        }
        #pragma unroll
        for (int r = 0; r < 2; ++r) {
            int e = tid + r * 256;          // 512 float4 of X tile (32k x 64n)
            int k = e >> 4, c4 = e & 15;
            *(float4*)(Xs + k*64 + c4*4) =
                *(const float4*)(x1 + ((size_t)(b * CIN_ + kc + k)) * N_ + n0 + c4*4);
        }
        __syncthreads();
        #pragma unroll
        for (int k = 0; k < 32; ++k) {
            float4 av = *(const float4*)(Ws + k*68 + ty*4);
            float4 bv = *(const float4*)(Xs + k*64 + tx*4);
            float a[4] = {av.x, av.y, av.z, av.w};
            float c[4] = {bv.x, bv.y, bv.z, bv.w};
            #pragma unroll
            for (int i = 0; i < 4; ++i)
                #pragma unroll
                for (int j = 0; j < 4; ++j)
                    acc[i][j] = fmaf(a[i], c[j], acc[i][j]);
        }
        __syncthreads();
    }

    // BN + ReLU, transpose via LDS, store f1t[b][n][c] (system-scope)
    float* S = sm; // [64][65]
    #pragma unroll
    for (int i = 0; i < 4; ++i) {
        int o = o0 + ty*4 + i;
        float sc = gam[o] / sqrtf(var[o] + 1e-5f);
        float sh = bet[o] - mu[o] * sc;
        #pragma unroll
        for (int j = 0; j < 4; ++j) {
            float v = fmaxf(acc[i][j] * sc + sh, 0.0f);
            S[(tx*4+j)*65 + ty*4+i] = v;
        }
    }
    __syncthreads();
    #pragma unroll
    for (int r = 0; r < 16; ++r) {
        int e = tid + r * 256;
        int n = e >> 6, o = e & 63;
        ws_store_f32(f1t + ((size_t)(b * N_) + n0 + n) * COUT_ + o0 + o, S[n*65 + o]);
    }
}

// ---------------------------------------------------------------------------
// Kernel B: three_nn + inverse-distance weights + p2 passthrough.
// ONE THREAD PER QUERY, sequential scan n=0..2047 (stable top-3, lex (d2,idx)).
// d^2 uses the exact arithmetic that passed pre-timing validation in round 4:
//   s   = fma(z,z, fma(y,y, x*x))   (ascending FMA chain)
//   dot = fma(z,z', fma(y,y', x*x'))
//   d2  = max(fma(-2, dot, s2 + s1), 0)
// All lanes read the same LDS address per iteration (broadcast, conflict-free).
// nn_idx/nn_w stores are system-scope (ws handoff).
// ---------------------------------------------------------------------------
__global__ __launch_bounds__(256) void three_nn_kernel(
    const float* __restrict__ p1, const float* __restrict__ p2,
    int* __restrict__ nn_idx, float* __restrict__ nn_w,
    float* __restrict__ out1)
{
    __shared__ float p1x[N_], p1y[N_], p1z[N_], s1[N_];
    const int b = blockIdx.y;
    for (int n = threadIdx.x; n < N_; n += 256) {
        float x = p1[((size_t)(b*N_)+n)*3 + 0];
        float y = p1[((size_t)(b*N_)+n)*3 + 1];
        float z = p1[((size_t)(b*N_)+n)*3 + 2];
        p1x[n] = x; p1y[n] = y; p1z[n] = z;
        float t = x * x;
        t = fmaf(y, y, t);
        t = fmaf(z, z, t);
        s1[n] = t;
    }
    __syncthreads();

    const int m = blockIdx.x * 256 + threadIdx.x;
    const size_t pbase = ((size_t)(b*M_) + m) * 3;
    const float qx = p2[pbase+0], qy = p2[pbase+1], qz = p2[pbase+2];
    float s2 = qx * qx;
    s2 = fmaf(qy, qy, s2);
    s2 = fmaf(qz, qz, s2);

    float D0 = FLT_MAX, D1 = FLT_MAX, D2 = FLT_MAX;
    int   I0 = 0x7fffffff, I1 = 0x7fffffff, I2 = 0x7fffffff;
    for (int n = 0; n < N_; ++n) {
        float dot = qx * p1x[n];
        dot = fmaf(qy, p1y[n], dot);
        dot = fmaf(qz, p1z[n], dot);
        float d2 = fmaf(-2.0f, dot, s2 + s1[n]);
        d2 = fmaxf(d2, 0.0f);
        // stable lex (d2, idx) insert; ascending n makes ties keep lower idx
        bool l0 = (d2 < D0);
        bool l1 = (d2 < D1);
        bool l2 = (d2 < D2);
        if (l2) {
            if (l0)      { D2=D1; I2=I1; D1=D0; I1=I0; D0=d2; I0=n; }
            else if (l1) { D2=D1; I2=I1; D1=d2;  I1=n; }
            else         { D2=d2;  I2=n; }
        }
    }
    float r0 = 1.0f / (D0 + 1e-8f);
    float r1 = 1.0f / (D1 + 1e-8f);
    float r2 = 1.0f / (D2 + 1e-8f);
    float sum = (r0 + r1) + r2;
    size_t o = ((size_t)(b*M_) + m) * 3;
    ws_store_u32(nn_idx + o+0, I0);
    ws_store_u32(nn_idx + o+1, I1);
    ws_store_u32(nn_idx + o+2, I2);
    ws_store_f32(nn_w + o+0, r0 / sum);
    ws_store_f32(nn_w + o+1, r1 / sum);
    ws_store_f32(nn_w + o+2, r2 / sum);
    out1[o+0] = qx; out1[o+1] = qy; out1[o+2] = qz;
}

// ---------------------------------------------------------------------------
// Kernel C: out0[b][c][m] = relu(bn(sum_ci w_lat[c,ci]*x2[b,ci,m]))
//                           + sum_k nn_w[b,m,k] * f1t[b][idx[b,m,k]][c]
// GEMM from x2 (inputs, normal loads); f1t/nn_idx/nn_w via system-scope loads.
// ---------------------------------------------------------------------------
__global__ __launch_bounds__(256) void lat_interp_kernel(
    const float* __restrict__ x2, const float* __restrict__ w,
    const float* __restrict__ gam, const float* __restrict__ bet,
    const float* __restrict__ mu, const float* __restrict__ var,
    const float* __restrict__ f1t, const int* __restrict__ nn_idx,
    const float* __restrict__ nn_w, float* __restrict__ out0)
{
    __shared__ float sm[4224];
    float* Ws = sm;          // [32][68]
    float* Xs = sm + 2176;   // [32][64]
    const int b = blockIdx.z;
    const int o0 = blockIdx.y * 64;
    const int m0 = blockIdx.x * 64;
    const int tid = threadIdx.x;
    const int tx = tid & 15, ty = tid >> 4;

    float acc[4][4] = {{0.f}};

    for (int kc = 0; kc < COUT_; kc += 32) {
        #pragma unroll
        for (int r = 0; r < 2; ++r) {
            int e = tid + r * 256;
            int o = e >> 3, k4 = e & 7;
            float4 v = *(const float4*)(w + (size_t)(o0 + o) * COUT_ + kc + k4 * 4);
            Ws[(k4*4+0)*68 + o] = v.x;
            Ws[(k4*4+1)*68 + o] = v.y;
            Ws[(k4*4+2)*68 + o] = v.z;
            Ws[(k4*4+3)*68 + o] = v.w;
        }
        #pragma unroll
        for (int r = 0; r < 2; ++r) {
            int e = tid + r * 256;
            int k = e >> 4, c4 = e & 15;
            *(float4*)(Xs + k*64 + c4*4) =
                *(const float4*)(x2 + ((size_t)(b * COUT_ + kc + k)) * M_ + m0 + c4*4);
        }
        __syncthreads();
        #pragma unroll
        for (int k = 0; k < 32; ++k) {
            float4 av = *(const float4*)(Ws + k*68 + ty*4);
            float4 bv = *(const float4*)(Xs + k*64 + tx*4);
            float a[4] = {av.x, av.y, av.z, av.w};
            float c[4] = {bv.x, bv.y, bv.z, bv.w};
            #pragma unroll
            for (int i = 0; i < 4; ++i)
                #pragma unroll
                for (int j = 0; j < 4; ++j)
                    acc[i][j] = fmaf(a[i], c[j], acc[i][j]);
        }
        __syncthreads();
    }

    const int mb = m0 + tx * 4;
    int   idx[4][3];
    float wq[4][3];
    #pragma unroll
    for (int j = 0; j < 4; ++j)
        #pragma unroll
        for (int k = 0; k < 3; ++k) {
            size_t o = ((size_t)(b*M_) + mb + j) * 3 + k;
            idx[j][k] = ws_load_u32(nn_idx + o);
            wq[j][k]  = ws_load_f32(nn_w + o);
        }

    float val[4][4];
    #pragma unroll
    for (int i = 0; i < 4; ++i) {
        int c = o0 + ty*4 + i;
        float sc = gam[c] / sqrtf(var[c] + 1e-5f);
        float sh = bet[c] - mu[c] * sc;
        #pragma unroll
        for (int j = 0; j < 4; ++j)
            val[i][j] = fmaxf(acc[i][j] * sc + sh, 0.0f);
    }
    #pragma unroll
    for (int j = 0; j < 4; ++j)
        #pragma unroll
        for (int k = 0; k < 3; ++k) {
            const float* gp = f1t + ((size_t)(b*N_) + idx[j][k]) * COUT_ + o0 + ty*4;
            float wk = wq[j][k];
            val[0][j] = fmaf(wk, ws_load_f32(gp + 0), val[0][j]);
            val[1][j] = fmaf(wk, ws_load_f32(gp + 1), val[1][j]);
            val[2][j] = fmaf(wk, ws_load_f32(gp + 2), val[2][j]);
            val[3][j] = fmaf(wk, ws_load_f32(gp + 3), val[3][j]);
        }
    #pragma unroll
    for (int i = 0; i < 4; ++i) {
        float4 o4 = make_float4(val[i][0], val[i][1], val[i][2], val[i][3]);
        *(float4*)(out0 + ((size_t)(b*COUT_) + o0 + ty*4 + i) * M_ + mb) = o4;
    }
}

// ---------------------------------------------------------------------------
extern "C" void kernel_launch(void* const* d_in, const int* in_sizes, int n_in,
                              void* d_out, int out_size, void* d_ws, size_t ws_size,
                              hipStream_t stream)
{
    (void)in_sizes; (void)n_in; (void)out_size; (void)ws_size;

    const float* x1    = (const float*)d_in[0];
    const float* p1    = (const float*)d_in[1];
    const float* x2    = (const float*)d_in[2];
    const float* p2    = (const float*)d_in[3];
    const float* w_up  = (const float*)d_in[4];
    const float* g_up  = (const float*)d_in[5];
    const float* b_up  = (const float*)d_in[6];
    const float* m_up  = (const float*)d_in[7];
    const float* v_up  = (const float*)d_in[8];
    const float* w_lat = (const float*)d_in[9];
    const float* g_lat = (const float*)d_in[10];
    const float* b_lat = (const float*)d_in[11];
    const float* m_lat = (const float*)d_in[12];
    const float* v_lat = (const float*)d_in[13];

    float* out0 = (float*)d_out;
    float* out1 = out0 + (size_t)B_ * COUT_ * M_;   // p2 passthrough

    // workspace layout: f1t (8 MB) | nn_idx (384 KB) | nn_w (384 KB)
    float* f1t   = (float*)d_ws;
    int*   nn_idx = (int*)((char*)d_ws + (size_t)B_ * N_ * COUT_ * 4);
    float* nn_w   = (float*)((char*)nn_idx + (size_t)B_ * M_ * 3 * 4);

    up_conv_kernel<<<dim3(N_/64, COUT_/64, B_), 256, 0, stream>>>(
        x1, w_up, g_up, b_up, m_up, v_up, f1t);
    three_nn_kernel<<<dim3(M_/256, B_), 256, 0, stream>>>(
        p1, p2, nn_idx, nn_w, out1);
    lat_interp_kernel<<<dim3(M_/64, COUT_/64, B_), 256, 0, stream>>>(
        x2, w_lat, g_lat, b_lat, m_lat, v_lat, f1t, nn_idx, nn_w, out0);
}